// Round 1
// baseline (218.150 us; speedup 1.0000x reference)
//
#include <hip/hip_runtime.h>

// Problem constants (match reference)
#define N_ 2048
#define D_ 16
#define O_ 3
#define S_ 10
#define E_ 4096
#define K_ 128

constexpr float STEP = 0.1f;           // (T_LAST - T_INIT) / S
constexpr int TILE = 128;
constexpr int T_ = N_ / TILE;          // 16 tile rows
constexpr int TP_ = T_ * (T_ + 1) / 2; // 136 triangular tile pairs
constexpr int PAIR_BLOCKS = S_ * TP_;  // 1360
constexpr int EVENT_BLOCKS = E_ / 2;   // 2048 (2 events per 256-thread block)
constexpr int GRID = PAIR_BLOCKS + EVENT_BLOCKS; // 3408
constexpr float LOG2E = 1.4426950408889634f;

struct PairSm {
    float xR[TILE][D_ + 1];   // +1 pad -> stride 17 (bank-conflict-free rows)
    float xC[TILE][D_ + 1];
    float sqR[TILE];
    float sqC[TILE];
    float gR[TILE];
    float gC[TILE];
};
struct EvSm {
    float dz[2][O_][D_];      // two events per block
};

__global__ __launch_bounds__(256) void nhpp_fused(
    const float* __restrict__ gamma,
    const float* __restrict__ z0,
    const float* __restrict__ et,
    const int* __restrict__ pairs,
    double* __restrict__ acc,
    unsigned* __restrict__ counter,
    float* __restrict__ out)
{
    __shared__ union { PairSm p; EvSm ev; } sm;
    __shared__ float wred[4];

    const int tid = threadIdx.x;
    const int bid = blockIdx.x;

    if (bid < PAIR_BLOCKS) {
        // ---------------- pairwise integral path ----------------
        const int s = bid / TP_;
        int rem = bid % TP_;
        int ti = 0;
        while (rem >= T_ - ti) { rem -= T_ - ti; ++ti; }
        const int tj = ti + rem;

        const float t  = STEP * (float)s;
        const float c1 = t;
        const float c2 = 0.5f * t * t;

        // build x tiles from z0 (x = z0_0 + t*z0_1 + t^2/2 * z0_2)
        for (int idx = tid; idx < TILE * D_; idx += 256) {
            const int r = idx >> 4, d = idx & 15;
            {
                const int n = ti * TILE + r;
                float v0 = z0[0 * N_ * D_ + n * D_ + d];
                float v1 = z0[1 * N_ * D_ + n * D_ + d];
                float v2 = z0[2 * N_ * D_ + n * D_ + d];
                sm.p.xR[r][d] = fmaf(c2, v2, fmaf(c1, v1, v0));
            }
            {
                const int n = tj * TILE + r;
                float v0 = z0[0 * N_ * D_ + n * D_ + d];
                float v1 = z0[1 * N_ * D_ + n * D_ + d];
                float v2 = z0[2 * N_ * D_ + n * D_ + d];
                sm.p.xC[r][d] = fmaf(c2, v2, fmaf(c1, v1, v0));
            }
        }
        __syncthreads();
        if (tid < TILE) {
            const int r = tid;
            float s0 = 0.f, s1 = 0.f;
            #pragma unroll
            for (int d = 0; d < D_; ++d) {
                s0 = fmaf(sm.p.xR[r][d], sm.p.xR[r][d], s0);
                s1 = fmaf(sm.p.xC[r][d], sm.p.xC[r][d], s1);
            }
            sm.p.sqR[r] = s0;
            sm.p.sqC[r] = s1;
            sm.p.gR[r] = gamma[ti * TILE + r];
            sm.p.gC[r] = gamma[tj * TILE + r];
        }
        __syncthreads();

        // 8x8 register micro-tile per thread; column rotation (j+tc)&7
        // makes the 16 distinct column addresses hit 16 distinct banks.
        const int tr = tid >> 4;   // 0..15
        const int tc = tid & 15;   // 0..15
        const int r0 = tr * 8, c0 = tc * 8;
        int cIdx[8];
        #pragma unroll
        for (int j = 0; j < 8; ++j) cIdx[j] = c0 + ((j + tc) & 7);

        float a8[8][8];
        #pragma unroll
        for (int i = 0; i < 8; ++i)
            #pragma unroll
            for (int j = 0; j < 8; ++j) a8[i][j] = 0.f;

        #pragma unroll
        for (int d = 0; d < D_; ++d) {
            float xr[8], xc[8];
            #pragma unroll
            for (int i = 0; i < 8; ++i) xr[i] = sm.p.xR[r0 + i][d];
            #pragma unroll
            for (int j = 0; j < 8; ++j) xc[j] = sm.p.xC[cIdx[j]][d];
            #pragma unroll
            for (int i = 0; i < 8; ++i)
                #pragma unroll
                for (int j = 0; j < 8; ++j)
                    a8[i][j] = fmaf(xr[i], xc[j], a8[i][j]);
        }

        float sqr[8], gr[8];
        #pragma unroll
        for (int i = 0; i < 8; ++i) {
            sqr[i] = sm.p.sqR[r0 + i];
            gr[i]  = sm.p.gR[r0 + i];
        }

        const int baseR = ti * TILE, baseC = tj * TILE;
        float lsum = 0.f;
        #pragma unroll
        for (int j = 0; j < 8; ++j) {
            const int cj = cIdx[j];
            const int m = baseC + cj;
            const float sqc = sm.p.sqC[cj];
            const float gc  = sm.p.gC[cj];
            #pragma unroll
            for (int i = 0; i < 8; ++i) {
                const int n = baseR + r0 + i;
                if (n < m) {
                    float d2 = sqr[i] + sqc - 2.0f * a8[i][j];
                    float dist = sqrtf(fmaxf(d2, 0.0f));
                    lsum += exp2f((gr[i] + gc - dist) * LOG2E);
                }
            }
        }

        // block reduce (4 waves)
        #pragma unroll
        for (int off = 32; off; off >>= 1) lsum += __shfl_down(lsum, off, 64);
        if ((tid & 63) == 0) wred[tid >> 6] = lsum;
        __syncthreads();
        if (tid == 0) {
            float b = wred[0] + wred[1] + wred[2] + wred[3];
            atomicAdd(acc, (double)(b * STEP));
        }
    } else {
        // ---------------- event log-intensity path ----------------
        const int bb = bid - PAIR_BLOCKS;
        const int g  = tid >> 7;        // 0/1: which event in this block
        const int lt = tid & 127;       // thread within event group (= k)
        const int e  = bb * 2 + g;

        if (lt < O_ * D_) {
            const int o = lt >> 4, d = lt & 15;
            const int i = pairs[e * 2 + 0];
            const int j = pairs[e * 2 + 1];
            const float inv = (o == 2) ? 0.5f : 1.0f;  // 1/fact
            sm.ev.dz[g][o][d] =
                (z0[o * N_ * D_ + i * D_ + d] - z0[o * N_ * D_ + j * D_ + d]) * inv;
        }
        __syncthreads();

        const float t = et[e * K_ + lt];
        float ss = 0.f;
        #pragma unroll
        for (int d = 0; d < D_; ++d) {
            // dv = dz0 + t*dz1 + t^2*(dz2/2)  (Horner)
            float v = fmaf(t, fmaf(t, sm.ev.dz[g][2][d], sm.ev.dz[g][1][d]),
                           sm.ev.dz[g][0][d]);
            ss = fmaf(v, v, ss);
        }
        float ed = sqrtf(fmaxf(ss, 0.0f));

        #pragma unroll
        for (int off = 32; off; off >>= 1) ed += __shfl_down(ed, off, 64);
        if ((tid & 63) == 0) wred[tid >> 6] = ed;
        __syncthreads();
        if (lt == 0) {
            const float sum_ed = wred[g * 2 + 0] + wred[g * 2 + 1];
            const int i = pairs[e * 2 + 0];
            const int j = pairs[e * 2 + 1];
            const float log_int = (float)K_ * (gamma[i] + gamma[j]) - sum_ed;
            atomicAdd(acc, (double)(-log_int));
        }
    }

    // ---------------- last-block finalize ----------------
    __syncthreads();
    if (tid == 0) {
        __threadfence();
        unsigned prev = atomicAdd(counter, 1u);
        if (prev == (unsigned)gridDim.x - 1u) {
            double v = atomicAdd(acc, 0.0);  // atomic read after all adds visible
            out[0] = (float)v;
        }
    }
}

extern "C" void kernel_launch(void* const* d_in, const int* in_sizes, int n_in,
                              void* d_out, int out_size, void* d_ws, size_t ws_size,
                              hipStream_t stream) {
    (void)in_sizes; (void)n_in; (void)out_size; (void)ws_size;
    const float* gamma = (const float*)d_in[0];
    const float* z0    = (const float*)d_in[1];
    const float* et    = (const float*)d_in[2];
    const int*   pairs = (const int*)d_in[3];
    float* out = (float*)d_out;

    double*   acc     = (double*)d_ws;
    unsigned* counter = (unsigned*)((char*)d_ws + 8);

    hipMemsetAsync(d_ws, 0, 16, stream);
    nhpp_fused<<<GRID, 256, 0, stream>>>(gamma, z0, et, pairs, acc, counter, out);
}

// Round 7
// 111.983 us; speedup vs baseline: 1.9481x; 1.9481x over previous
//
#include <hip/hip_runtime.h>

// Problem constants (match reference)
#define N_ 2048
#define D_ 16
#define O_ 3
#define S_ 10
#define E_ 4096
#define K_ 128

constexpr float STEP = 0.1f;            // (T_LAST - T_INIT) / S
constexpr int TILE = 128;
constexpr int T_ = N_ / TILE;           // 16 tile rows
constexpr int TP_ = T_ * (T_ + 1) / 2;  // 136 triangular tile pairs
constexpr int PAIR_BLOCKS = S_ * TP_;   // 1360
constexpr int EVENT_BLOCKS = E_ / 4;    // 1024 (4 events per block, 1 per wave)
constexpr int GRID = PAIR_BLOCKS + EVENT_BLOCKS; // 2384
constexpr int NSLOT = 64;               // accumulator slots (contention /64)
constexpr float LOG2E = 1.4426950408889634f;

struct PairSm {
    // row stride = 9 float2 = 72 B: 8B-aligned for ds_read_b64, and
    // 18-word stride makes micro-kernel reads <=2-way bank conflicts
    // (free per m136) given chunk rotation ce = (cc + (tc>>1)) & 7.
    float2 xR[TILE][9];
    float2 xC[TILE][9];
    float sqR[TILE];
    float sqC[TILE];
    float gR[TILE];   // gamma * LOG2E
    float gC[TILE];
};
struct EvSm {
    float dz[4][O_][D_];   // four events per block (one per wave)
};

__global__ __launch_bounds__(256, 3) void nhpp_fused(
    const float* __restrict__ gamma,
    const float* __restrict__ z0,
    const float* __restrict__ et,
    const int* __restrict__ pairs,
    double* __restrict__ slots,      // [NSLOT]
    unsigned* __restrict__ counter,
    float* __restrict__ out)
{
    __shared__ union { PairSm p; EvSm ev; } sm;
    __shared__ float wred[4];
    __shared__ int lastFlag;

    const int tid = threadIdx.x;
    const int bid = blockIdx.x;

    if (bid < PAIR_BLOCKS) {
        // ---------------- pairwise integral path ----------------
        const int s = bid / TP_;
        int rem = bid % TP_;
        int ti = 0;
        while (rem >= T_ - ti) { rem -= T_ - ti; ++ti; }
        const int tj = ti + rem;
        const bool diag = (ti == tj);

        const float t  = STEP * (float)s;
        const float c1 = t;
        const float c2 = 0.5f * t * t;

        // stage both x tiles as float2 chunks: 2 tiles * 128 rows * 8 chunks
        // = 2048 float2 -> 8 iterations of 256 threads. Coalesced global
        // float2 loads.
        #pragma unroll
        for (int it = 0; it < 8; ++it) {
            const int e4   = it * 256 + tid;
            const int r    = (e4 >> 3) & 127;
            const int ch   = e4 & 7;
            const int n    = ((it < 4) ? ti : tj) * TILE + r;
            const float* p0 = z0 + (0 * N_ + n) * D_ + 2 * ch;
            const float2 v0 = *(const float2*)(p0);
            const float2 v1 = *(const float2*)(p0 + N_ * D_);
            const float2 v2 = *(const float2*)(p0 + 2 * N_ * D_);
            float2 x;
            x.x = fmaf(c2, v2.x, fmaf(c1, v1.x, v0.x));
            x.y = fmaf(c2, v2.y, fmaf(c1, v1.y, v0.y));
            if (it < 4) sm.p.xR[r][ch] = x;
            else        sm.p.xC[r][ch] = x;
        }
        __syncthreads();

        // per-row |x|^2 and gamma*LOG2E
        {
            const int r = tid & 127;
            const float2* row = (tid < 128) ? sm.p.xR[r] : sm.p.xC[r];
            float ssq = 0.f;
            #pragma unroll
            for (int ch = 0; ch < 8; ++ch) {
                float2 v = row[ch];
                ssq = fmaf(v.x, v.x, fmaf(v.y, v.y, ssq));
            }
            const int n = ((tid < 128) ? ti : tj) * TILE + r;
            const float gl = gamma[n] * LOG2E;
            if (tid < 128) { sm.p.sqR[r] = ssq; sm.p.gR[r] = gl; }
            else           { sm.p.sqC[r] = ssq; sm.p.gC[r] = gl; }
        }
        __syncthreads();

        // 8x8 register micro-tile, d processed as 8 float2 chunks with
        // per-thread rotation -> ds_read_b64, <=2-way conflicts.
        const int tr = tid >> 4;    // 0..15
        const int tc = tid & 15;    // 0..15
        const int r0 = tr * 8, c0 = tc * 8;
        const int rot = (tc >> 1) & 7;

        float a8[8][8];
        #pragma unroll
        for (int i = 0; i < 8; ++i)
            #pragma unroll
            for (int j = 0; j < 8; ++j) a8[i][j] = 0.f;

        #pragma unroll
        for (int cc = 0; cc < 8; ++cc) {
            const int ce = (cc + rot) & 7;
            float2 xr[8], xc[8];
            #pragma unroll
            for (int i = 0; i < 8; ++i) xr[i] = sm.p.xR[r0 + i][ce];
            #pragma unroll
            for (int j = 0; j < 8; ++j) xc[j] = sm.p.xC[c0 + j][ce];
            #pragma unroll
            for (int i = 0; i < 8; ++i)
                #pragma unroll
                for (int j = 0; j < 8; ++j)
                    a8[i][j] = fmaf(xr[i].x, xc[j].x,
                               fmaf(xr[i].y, xc[j].y, a8[i][j]));
        }

        float sqr[8], grl[8];
        #pragma unroll
        for (int i = 0; i < 8; ++i) {
            sqr[i] = sm.p.sqR[r0 + i];
            grl[i] = sm.p.gR[r0 + i];
        }

        float ls0 = 0.f, ls1 = 0.f;
        #pragma unroll
        for (int j = 0; j < 8; ++j) {
            const float sqc = sm.p.sqC[c0 + j];
            const float gcl = sm.p.gC[c0 + j];
            #pragma unroll
            for (int i = 0; i < 8; ++i) {
                const float d2   = fmaf(-2.0f, a8[i][j], sqr[i] + sqc);
                const float dist = sqrtf(fmaxf(d2, 0.0f));
                float v = exp2f(fmaf(-LOG2E, dist, grl[i] + gcl));
                if (diag) v = (r0 + i < c0 + j) ? v : 0.f;
                if (i & 1) ls1 += v; else ls0 += v;
            }
        }
        float lsum = ls0 + ls1;

        #pragma unroll
        for (int off = 32; off; off >>= 1) lsum += __shfl_down(lsum, off, 64);
        if ((tid & 63) == 0) wred[tid >> 6] = lsum;
        __syncthreads();
        if (tid == 0) {
            const float b = wred[0] + wred[1] + wred[2] + wred[3];
            atomicAdd(&slots[bid & (NSLOT - 1)], (double)(b * STEP));
        }
    } else {
        // ---------------- event log-intensity path ----------------
        const int bb   = bid - PAIR_BLOCKS;
        const int w    = tid >> 6;       // wave = event slot
        const int lane = tid & 63;
        const int e    = bb * 4 + w;
        const int pi   = pairs[2 * e + 0];
        const int pj   = pairs[2 * e + 1];

        if (lane < O_ * D_) {
            const int o = lane >> 4, d = lane & 15;
            const float inv = (o == 2) ? 0.5f : 1.0f;   // 1/fact
            sm.ev.dz[w][o][d] =
                (z0[(o * N_ + pi) * D_ + d] - z0[(o * N_ + pj) * D_ + d]) * inv;
        }
        __syncthreads();

        const float2 tt = *(const float2*)(et + e * K_ + 2 * lane);
        float ed = 0.f;
        #pragma unroll
        for (int h = 0; h < 2; ++h) {
            const float tk = (h == 0) ? tt.x : tt.y;
            float ss = 0.f;
            #pragma unroll
            for (int d = 0; d < D_; ++d) {
                const float v = fmaf(tk, fmaf(tk, sm.ev.dz[w][2][d],
                                              sm.ev.dz[w][1][d]),
                                     sm.ev.dz[w][0][d]);
                ss = fmaf(v, v, ss);
            }
            ed += sqrtf(fmaxf(ss, 0.0f));
        }
        #pragma unroll
        for (int off = 32; off; off >>= 1) ed += __shfl_down(ed, off, 64);
        if (lane == 0) {
            const float part = ed - (float)K_ * (gamma[pi] + gamma[pj]);
            atomicAdd(&slots[bid & (NSLOT - 1)], (double)part);
        }
        __syncthreads();   // keep barrier count uniform with pair path
    }

    // ---------------- last-block finalize ----------------
    __syncthreads();
    if (tid == 0) {
        __threadfence();
        const unsigned prev = atomicAdd(counter, 1u);
        lastFlag = (prev == (unsigned)(GRID - 1)) ? 1 : 0;
    }
    __syncthreads();
    if (lastFlag && tid < NSLOT) {
        double v = atomicAdd(&slots[tid], 0.0);   // coherent read of final value
        #pragma unroll
        for (int off = 32; off; off >>= 1) v += __shfl_down(v, off, 64);
        if (tid == 0) out[0] = (float)v;
    }
}

extern "C" void kernel_launch(void* const* d_in, const int* in_sizes, int n_in,
                              void* d_out, int out_size, void* d_ws, size_t ws_size,
                              hipStream_t stream) {
    (void)in_sizes; (void)n_in; (void)out_size; (void)ws_size;
    const float* gamma = (const float*)d_in[0];
    const float* z0    = (const float*)d_in[1];
    const float* et    = (const float*)d_in[2];
    const int*   pairs = (const int*)d_in[3];
    float* out = (float*)d_out;

    double*   slots   = (double*)d_ws;
    unsigned* counter = (unsigned*)((char*)d_ws + NSLOT * 8);

    hipMemsetAsync(d_ws, 0, NSLOT * 8 + 16, stream);
    nhpp_fused<<<GRID, 256, 0, stream>>>(gamma, z0, et, pairs, slots, counter, out);
}

// Round 11
// 88.149 us; speedup vs baseline: 2.4748x; 1.2704x over previous
//
#include <hip/hip_runtime.h>

// Problem constants (match reference)
#define N_ 2048
#define D_ 16
#define O_ 3
#define S_ 10
#define E_ 4096
#define K_ 128

constexpr float STEP = 0.1f;            // (T_LAST - T_INIT) / S
constexpr int TILE = 128;
constexpr int T_ = N_ / TILE;           // 16 tile rows
constexpr int TP_ = T_ * (T_ + 1) / 2;  // 136 triangular tile pairs
constexpr int PAIR_BLOCKS = S_ * TP_;   // 1360
constexpr int EVENT_BLOCKS = E_ / 8;    // 512 (8 events per block, 1 per wave)
constexpr int GRID = PAIR_BLOCKS + EVENT_BLOCKS; // 1872
constexpr float LOG2E = 1.4426950408889634f;

struct PairSm {
    // row stride = 9 float2 = 72 B: 8B-aligned ds_read_b64; with chunk
    // rotation ce=(cc+(tc>>1))&7, row reads are broadcast-pairs (free)
    // and column reads are <=2-way (free per m136).
    float2 xR[TILE][9];
    float2 xC[TILE][9];
    float sqR[TILE];
    float sqC[TILE];
    float gR[TILE];   // gamma * LOG2E
    float gC[TILE];
};
struct EvSm {
    float dz[8][O_][D_];   // eight events per block (one per wave)
};

// 512 threads, 4x8 micro-tile: 32 accumulators + 24 operand regs — fits
// the arch VGPR file (no __launch_bounds__ min-waves: avoid AGPR shuffling
// seen at R7 where VGPR_Count=52 forced accvgpr_read/write around FMAs).
__global__ __launch_bounds__(512) void nhpp_main(
    const float* __restrict__ gamma,
    const float* __restrict__ z0,
    const float* __restrict__ et,
    const int* __restrict__ pairs,
    double* __restrict__ slots)      // [GRID], one per block, no atomics
{
    __shared__ union { PairSm p; EvSm ev; } sm;
    __shared__ float wred[8];

    const int tid = threadIdx.x;
    const int bid = blockIdx.x;

    if (bid < PAIR_BLOCKS) {
        // ---------------- pairwise integral path ----------------
        const int s = bid / TP_;
        int rem = bid % TP_;
        int ti = 0;
        while (rem >= T_ - ti) { rem -= T_ - ti; ++ti; }
        const int tj = ti + rem;
        const bool diag = (ti == tj);

        const float t  = STEP * (float)s;
        const float c1 = t;
        const float c2 = 0.5f * t * t;

        // stage both x tiles: 2 tiles * 128 rows * 8 float2-chunks = 2048
        // float2 -> 4 iterations of 512 threads; coalesced float2 loads.
        #pragma unroll
        for (int it = 0; it < 4; ++it) {
            const int e4 = it * 512 + tid;
            const int r  = (e4 >> 3) & 127;
            const int ch = e4 & 7;
            const int n  = ((it < 2) ? ti : tj) * TILE + r;
            const float* p0 = z0 + (0 * N_ + n) * D_ + 2 * ch;
            const float2 v0 = *(const float2*)(p0);
            const float2 v1 = *(const float2*)(p0 + N_ * D_);
            const float2 v2 = *(const float2*)(p0 + 2 * N_ * D_);
            float2 x;
            x.x = fmaf(c2, v2.x, fmaf(c1, v1.x, v0.x));
            x.y = fmaf(c2, v2.y, fmaf(c1, v1.y, v0.y));
            if (it < 2) sm.p.xR[r][ch] = x;
            else        sm.p.xC[r][ch] = x;
        }
        __syncthreads();

        // per-row |x|^2 and gamma*LOG2E (threads 0..255)
        if (tid < 256) {
            const int r = tid & 127;
            const float2* row = (tid < 128) ? sm.p.xR[r] : sm.p.xC[r];
            float ssq = 0.f;
            #pragma unroll
            for (int ch = 0; ch < 8; ++ch) {
                const float2 v = row[ch];
                ssq = fmaf(v.x, v.x, fmaf(v.y, v.y, ssq));
            }
            const int n = ((tid < 128) ? ti : tj) * TILE + r;
            const float gl = gamma[n] * LOG2E;
            if (tid < 128) { sm.p.sqR[r] = ssq; sm.p.gR[r] = gl; }
            else           { sm.p.sqC[r] = ssq; sm.p.gC[r] = gl; }
        }
        __syncthreads();

        // 4x8 register micro-tile over a 128x128 tile (32 x 16 threads).
        const int tr = tid >> 4;    // 0..31
        const int tc = tid & 15;    // 0..15
        const int r0 = tr * 4, c0 = tc * 8;
        const int rot = (tc >> 1) & 7;

        float a8[4][8];
        #pragma unroll
        for (int i = 0; i < 4; ++i)
            #pragma unroll
            for (int j = 0; j < 8; ++j) a8[i][j] = 0.f;

        #pragma unroll
        for (int cc = 0; cc < 8; ++cc) {
            const int ce = (cc + rot) & 7;
            float2 xr[4], xc[8];
            #pragma unroll
            for (int i = 0; i < 4; ++i) xr[i] = sm.p.xR[r0 + i][ce];
            #pragma unroll
            for (int j = 0; j < 8; ++j) xc[j] = sm.p.xC[c0 + j][ce];
            #pragma unroll
            for (int i = 0; i < 4; ++i)
                #pragma unroll
                for (int j = 0; j < 8; ++j)
                    a8[i][j] = fmaf(xr[i].x, xc[j].x,
                               fmaf(xr[i].y, xc[j].y, a8[i][j]));
        }

        float sqr[4], grl[4];
        #pragma unroll
        for (int i = 0; i < 4; ++i) {
            sqr[i] = sm.p.sqR[r0 + i];
            grl[i] = sm.p.gR[r0 + i];
        }

        float ls0 = 0.f, ls1 = 0.f;
        #pragma unroll
        for (int j = 0; j < 8; ++j) {
            const float sqc = sm.p.sqC[c0 + j];
            const float gcl = sm.p.gC[c0 + j];
            #pragma unroll
            for (int i = 0; i < 4; ++i) {
                const float d2   = fmaf(-2.0f, a8[i][j], sqr[i] + sqc);
                const float dist = sqrtf(fmaxf(d2, 0.0f));
                float v = exp2f(fmaf(-LOG2E, dist, grl[i] + gcl));
                if (diag) v = (r0 + i < c0 + j) ? v : 0.f;
                if (i & 1) ls1 += v; else ls0 += v;
            }
        }
        float lsum = ls0 + ls1;

        #pragma unroll
        for (int off = 32; off; off >>= 1) lsum += __shfl_down(lsum, off, 64);
        if ((tid & 63) == 0) wred[tid >> 6] = lsum;
        __syncthreads();
        if (tid == 0) {
            float b = 0.f;
            #pragma unroll
            for (int k = 0; k < 8; ++k) b += wred[k];
            slots[bid] = (double)(b * STEP);
        }
    } else {
        // ---------------- event log-intensity path ----------------
        const int bb   = bid - PAIR_BLOCKS;
        const int w    = tid >> 6;       // wave = event slot (0..7)
        const int lane = tid & 63;
        const int e    = bb * 8 + w;
        const int pi   = pairs[2 * e + 0];
        const int pj   = pairs[2 * e + 1];

        if (lane < O_ * D_) {
            const int o = lane >> 4, d = lane & 15;
            const float inv = (o == 2) ? 0.5f : 1.0f;   // 1/fact
            sm.ev.dz[w][o][d] =
                (z0[(o * N_ + pi) * D_ + d] - z0[(o * N_ + pj) * D_ + d]) * inv;
        }
        __syncthreads();

        const float2 tt = *(const float2*)(et + e * K_ + 2 * lane);
        float ed = 0.f;
        #pragma unroll
        for (int h = 0; h < 2; ++h) {
            const float tk = (h == 0) ? tt.x : tt.y;
            float ss = 0.f;
            #pragma unroll
            for (int d = 0; d < D_; ++d) {
                const float v = fmaf(tk, fmaf(tk, sm.ev.dz[w][2][d],
                                              sm.ev.dz[w][1][d]),
                                     sm.ev.dz[w][0][d]);
                ss = fmaf(v, v, ss);
            }
            ed += sqrtf(fmaxf(ss, 0.0f));
        }
        #pragma unroll
        for (int off = 32; off; off >>= 1) ed += __shfl_down(ed, off, 64);
        if (lane == 0)
            wred[w] = ed - (float)K_ * (gamma[pi] + gamma[pj]); // = -log_int
        __syncthreads();
        if (tid == 0) {
            float b = 0.f;
            #pragma unroll
            for (int k = 0; k < 8; ++k) b += wred[k];
            slots[bid] = (double)b;
        }
    }
}

// Final reduction over per-block partials — separate dispatch, so no
// atomic counter / memset needed (every slot is written unconditionally
// by its block; harness poison is always overwritten).
__global__ __launch_bounds__(512) void nhpp_reduce(
    const double* __restrict__ slots, float* __restrict__ out)
{
    __shared__ double w8[8];
    const int tid = threadIdx.x;
    double s = 0.0;
    for (int i = tid; i < GRID; i += 512) s += slots[i];
    #pragma unroll
    for (int off = 32; off; off >>= 1) s += __shfl_down(s, off, 64);
    if ((tid & 63) == 0) w8[tid >> 6] = s;
    __syncthreads();
    if (tid == 0) {
        double t = 0.0;
        #pragma unroll
        for (int k = 0; k < 8; ++k) t += w8[k];
        out[0] = (float)t;
    }
}

extern "C" void kernel_launch(void* const* d_in, const int* in_sizes, int n_in,
                              void* d_out, int out_size, void* d_ws, size_t ws_size,
                              hipStream_t stream) {
    (void)in_sizes; (void)n_in; (void)out_size; (void)ws_size;
    const float* gamma = (const float*)d_in[0];
    const float* z0    = (const float*)d_in[1];
    const float* et    = (const float*)d_in[2];
    const int*   pairs = (const int*)d_in[3];
    float* out = (float*)d_out;

    double* slots = (double*)d_ws;   // GRID * 8 B = 15 KB

    nhpp_main<<<GRID, 512, 0, stream>>>(gamma, z0, et, pairs, slots);
    nhpp_reduce<<<1, 512, 0, stream>>>(slots, out);
}